// Round 10
// baseline (220.432 us; speedup 1.0000x reference)
//
#include <hip/hip_runtime.h>
#include <hip/hip_bf16.h>

// LSH Attention, MI355X gfx950.  6-dispatch pipeline:
//  1) k_prep  (z-branch): transW x4, x->bf16 cast, P=W@R^T fold + 3-split,
//     bterm
//  2) k_main  (y-branch): Q/K/V projection GEMM (m97-style 128x128,
//     global_load_lds width-16; Q prescaled by 0.125 = 1/sqrt(DK), exact)
//     + bucket-logit GEMM partials (6-term split-bf16, K-split x4, 128x64
//     tiles -- MFMA:ds_read 48:18 vs old 24:15; grid (32,40), no dead
//     blocks).  x loaded sync fp32 + split3 in-register (R8: all-async
//     6-stream staging serializes the LDS-DMA queue, -19us).
//  3) k_amax: deterministic fixed-order partial reduction + bterm + argmax
//  4) k_sort: per-(b,h) counting sort by bucket (wave-parallel prefix scan)
//  5) k_attn: bucket-sorted flash attention, double-buffered K/V (1 barrier
//     per tile; P-relayout is wave-private so needs no barrier)
//  6) k_gout: output GEMM 64x128 tiles -> fp32 d_out
//
// MFMA 16x16x32 bf16 layouts (verified in guide):
//  A: lane holds A[m=lane&15][k=(lane>>4)*8+j]
//  B: lane holds B[k=(lane>>4)*8+j][n=lane&15]
//  C/D: lane holds D[m=(lane>>4)*4+r][n=lane&15]

typedef __bf16 bf16;
typedef __bf16 bf16x8 __attribute__((ext_vector_type(8)));
typedef __bf16 bf16x4 __attribute__((ext_vector_type(4)));
typedef float f32x4 __attribute__((ext_vector_type(4)));

#define DEV static __device__ __forceinline__

DEV f32x4 zero4() { f32x4 z; z[0]=0.f; z[1]=0.f; z[2]=0.f; z[3]=0.f; return z; }

DEV f32x4 mfma_bf16(bf16x8 a, bf16x8 b, f32x4 c) {
  return __builtin_amdgcn_mfma_f32_16x16x32_bf16(a, b, c, 0, 0, 0);
}

// async global->LDS, 16B/lane; LDS dest = wave-uniform base + lane*16
DEV void load_lds16(const bf16* g, bf16* l) {
  __builtin_amdgcn_global_load_lds(
      (const __attribute__((address_space(1))) void*)g,
      (__attribute__((address_space(3))) void*)l, 16, 0, 0);
}

DEV void split3(float f, bf16& h, bf16& m, bf16& l) {
  h = (bf16)f;
  float rm = f - (float)h;
  m = (bf16)rm;
  l = (bf16)(rm - (float)m);
}

#define B_  2
#define S_  2048
#define D_  1024
#define H_  16
#define NH_ 8
#define DK_ 64
#define M_  4096   // B_*S_
#define QPAD 2560  // 2048 + 8*64 (per-bucket 64-alignment padding)
#define NQT  40    // max q-tiles per (b,h): 32 + 8

// ---------------------------------------------------------------- prep
// z<4: transW (64x64 transpose+cast); z=4: x->bf16; z=5 (64 blocks):
// P[d][c]=W(:,h*64:)@R[n]^T fold, 3-split transposed write, + bterm.
__global__ __launch_bounds__(256) void k_prep(
    const float* __restrict__ Wq, const float* __restrict__ Wk,
    const float* __restrict__ Wv, const float* __restrict__ Wo,
    const float* __restrict__ x, const float* __restrict__ bq,
    const float* __restrict__ bk, const float* __restrict__ R,
    bf16* __restrict__ Wtq, bf16* __restrict__ Wtk,
    bf16* __restrict__ Wtv, bf16* __restrict__ Wto,
    bf16* __restrict__ xh, bf16* __restrict__ Pth, bf16* __restrict__ Ptm,
    bf16* __restrict__ Ptl, float* __restrict__ bt) {
  __shared__ float tile[64][65];
  __shared__ float Rl[512];
  const int t = threadIdx.x;
  const int z = blockIdx.z;
  if (z < 4) {
    const float* W = z == 0 ? Wq : z == 1 ? Wk : z == 2 ? Wv : Wo;
    bf16* Wt = z == 0 ? Wtq : z == 1 ? Wtk : z == 2 ? Wtv : Wto;
    int k0 = blockIdx.x * 64, n0 = blockIdx.y * 64;
    int c = t & 63, r4 = t >> 6;
#pragma unroll
    for (int i = 0; i < 16; i++) {
      int r = r4 * 16 + i;
      tile[r][c] = W[(k0 + r) * D_ + n0 + c];
    }
    __syncthreads();
#pragma unroll
    for (int i = 0; i < 16; i++) {
      int r = r4 * 16 + i;
      Wt[(n0 + r) * D_ + k0 + c] = (bf16)tile[c][r];
    }
  } else if (z == 4) {
    int bid = blockIdx.y * 16 + blockIdx.x;
    int base = bid * 16384 + t * 4;
#pragma unroll 4
    for (int it = 0; it < 16; it++) {
      int i = base + it * 1024;
      f32x4 v = *(const f32x4*)(x + i);
      bf16x4 o;
#pragma unroll
      for (int j = 0; j < 4; j++) o[j] = (bf16)v[j];
      *(bf16x4*)(xh + i) = o;
    }
  } else {
    int bid = blockIdx.y * 16 + blockIdx.x;
    if (bid >= 64) return;
    Rl[t] = R[t];
    Rl[t + 256] = R[t + 256];
    __syncthreads();
    const int d0 = bid * 16;
    const int sel = t >> 7, hn = t & 127, h = hn >> 3, n = hn & 7;
    const float* W = sel ? Wk : Wq;
    const float* Rr = &Rl[n * 64];
    bf16x8 vh[2], vm[2], vl[2];
#pragma unroll
    for (int dl = 0; dl < 16; dl++) {
      const float* wr = W + (d0 + dl) * D_ + h * 64;
      float acc = 0.f;
#pragma unroll
      for (int k = 0; k < 64; k += 4) {
        f32x4 wv = *(const f32x4*)(wr + k);
        acc += (wv[0] * Rr[k] + wv[1] * Rr[k + 1]) +
               (wv[2] * Rr[k + 2] + wv[3] * Rr[k + 3]);
      }
      bf16 hh, mm, ll;
      split3(acc, hh, mm, ll);
      vh[dl >> 3][dl & 7] = hh;
      vm[dl >> 3][dl & 7] = mm;
      vl[dl >> 3][dl & 7] = ll;
    }
    *(bf16x8*)&Pth[t * D_ + d0] = vh[0];
    *(bf16x8*)&Pth[t * D_ + d0 + 8] = vh[1];
    *(bf16x8*)&Ptm[t * D_ + d0] = vm[0];
    *(bf16x8*)&Ptm[t * D_ + d0 + 8] = vm[1];
    *(bf16x8*)&Ptl[t * D_ + d0] = vl[0];
    *(bf16x8*)&Ptl[t * D_ + d0 + 8] = vl[1];
    if (bid == 0) {
      const float* bb = sel ? bk : bq;
      float acc = 0.f;
#pragma unroll 8
      for (int k = 0; k < 64; k++) acc += bb[h * 64 + k] * Rr[k];
      bt[t] = acc;
    }
  }
}

// ---------------------------------------------------------------- main fused
// grid (32, 40).  y<24: QKV projection GEMM, 128x128 tile, mat=y>>3,
// n0=(y&7)*128, m0=x*128.  Q (mat 0) prescaled by 0.125 (exact pow2).
// y in 24..39: bucket-logit GEMM partial, chunk=(y-24)>>2, n0=((y-24)&3)*64,
// m0=x*128 (128-row tile), K in [chunk*256,+256): 6-term split-bf16, x
// sync-loaded fp32 + in-register split3 overlapping 3 async P streams,
// fp32 partial -> Lpart[chunk].
__global__ __launch_bounds__(256) void k_main(
    const float* __restrict__ x, const bf16* __restrict__ xh,
    const bf16* __restrict__ Wtq, const bf16* __restrict__ Wtk,
    const bf16* __restrict__ Wtv, const float* __restrict__ bq,
    const float* __restrict__ bk, const float* __restrict__ bv,
    const bf16* __restrict__ Pth, const bf16* __restrict__ Ptm,
    const bf16* __restrict__ Ptl,
    bf16* __restrict__ Qb, bf16* __restrict__ Kb, bf16* __restrict__ Vb,
    float* __restrict__ Lpart) {
  __shared__ __align__(16) bf16 S[18432];  // 36 KB union
  const int t = threadIdx.x;
  const int lane = t & 63, w = t >> 6;
  const int lm = lane & 15, qd = lane >> 4;
  const int srow = lane >> 2, sseg = lane & 3;  // 16 rows x 4 segs per instr

  if (blockIdx.y < 24) {  // ---------------- QKV GEMM
    bf16* Al = &S[0];     // 128x32
    bf16* Bl = &S[4096];  // 128x32
    const int m0 = blockIdx.x * 128;
    const int mat = blockIdx.y >> 3;
    const int n0 = (blockIdx.y & 7) * 128;
    const bf16* Bt = mat == 0 ? Wtq : (mat == 1 ? Wtk : Wtv);
    const float* bias = mat == 0 ? bq : (mat == 1 ? bk : bv);
    bf16* out = mat == 0 ? Qb : (mat == 1 ? Kb : Vb);
    const float osc = mat == 0 ? 0.125f : 1.f;  // fold 1/sqrt(DK) into Q
    const int wm = w >> 1, wn = w & 1;

    f32x4 acc[4][4];
#pragma unroll
    for (int i = 0; i < 4; i++)
#pragma unroll
      for (int j = 0; j < 4; j++) acc[i][j] = zero4();

    for (int k0 = 0; k0 < D_; k0 += 32) {
      __syncthreads();
      load_lds16(&xh[(m0 + w * 16 + srow) * D_ + k0 + sseg * 8],
                 &Al[(w * 16) * 32]);
      load_lds16(&xh[(m0 + 64 + w * 16 + srow) * D_ + k0 + sseg * 8],
                 &Al[(64 + w * 16) * 32]);
      load_lds16(&Bt[(n0 + w * 16 + srow) * D_ + k0 + sseg * 8],
                 &Bl[(w * 16) * 32]);
      load_lds16(&Bt[(n0 + 64 + w * 16 + srow) * D_ + k0 + sseg * 8],
                 &Bl[(64 + w * 16) * 32]);
      __syncthreads();
      bf16x8 af[4], bfr[4];
#pragma unroll
      for (int i = 0; i < 4; i++)
        af[i] = *(const bf16x8*)&Al[(wm * 64 + i * 16 + lm) * 32 + qd * 8];
#pragma unroll
      for (int j = 0; j < 4; j++)
        bfr[j] = *(const bf16x8*)&Bl[(wn * 64 + j * 16 + lm) * 32 + qd * 8];
#pragma unroll
      for (int i = 0; i < 4; i++)
#pragma unroll
        for (int j = 0; j < 4; j++)
          acc[i][j] = mfma_bf16(af[i], bfr[j], acc[i][j]);
    }
#pragma unroll
    for (int j = 0; j < 4; j++) {
      int n = n0 + wn * 64 + j * 16 + lm;
      float bv2 = bias[n];
#pragma unroll
      for (int i = 0; i < 4; i++) {
        int mbase = m0 + wm * 64 + i * 16 + qd * 4;
#pragma unroll
        for (int r = 0; r < 4; r++) {
          int m = mbase + r;
          int bb = m >> 11, s = m & 2047, hh = n >> 6, d = n & 63;
          out[((bb * H_ + hh) * S_ + s) * DK_ + d] =
              (bf16)((acc[i][j][r] + bv2) * osc);
        }
      }
    }
  } else {  // ---------------- bucket-logit GEMM partial (K-split x4)
    bf16* SA0 = &S[0];      // 3 x 128x32 (stride 4096)
    bf16* SB0 = &S[12288];  // 3 x 64x32  (stride 2048)
    const int yy = blockIdx.y - 24;
    const int chunk = yy >> 2;
    const int m0 = blockIdx.x * 128, n0 = (yy & 3) * 64;
    f32x4 acc[2][4];
#pragma unroll
    for (int i2 = 0; i2 < 2; i2++)
#pragma unroll
      for (int nb = 0; nb < 4; nb++) acc[i2][nb] = zero4();
    const int xrow = t >> 1, xc = (t & 1) * 16;
    const int kbeg = chunk * 256, kend = kbeg + 256;

    for (int k0 = kbeg; k0 < kend; k0 += 32) {
      __syncthreads();
      // x fp32 (128 rows x 32 cols) -> 3-way bf16 split in-register -> LDS
      const float* xp = &x[(m0 + xrow) * D_ + k0 + xc];
      f32x4 xa0 = *(const f32x4*)(xp + 0);
      f32x4 xa1 = *(const f32x4*)(xp + 4);
      f32x4 xa2 = *(const f32x4*)(xp + 8);
      f32x4 xa3 = *(const f32x4*)(xp + 12);
      // P splits: async, wave w stages quarter w of each array
      load_lds16(&Pth[(n0 + w * 16 + srow) * D_ + k0 + sseg * 8],
                 &SB0[0 * 2048 + (w * 16) * 32]);
      load_lds16(&Ptm[(n0 + w * 16 + srow) * D_ + k0 + sseg * 8],
                 &SB0[1 * 2048 + (w * 16) * 32]);
      load_lds16(&Ptl[(n0 + w * 16 + srow) * D_ + k0 + sseg * 8],
                 &SB0[2 * 2048 + (w * 16) * 32]);
      bf16x8 vh0, vm0, vl0, vh1, vm1, vl1;
#pragma unroll
      for (int j = 0; j < 4; j++) {
        bf16 hh, mm, ll;
        split3(xa0[j], hh, mm, ll);
        vh0[j] = hh; vm0[j] = mm; vl0[j] = ll;
        split3(xa1[j], hh, mm, ll);
        vh0[4 + j] = hh; vm0[4 + j] = mm; vl0[4 + j] = ll;
        split3(xa2[j], hh, mm, ll);
        vh1[j] = hh; vm1[j] = mm; vl1[j] = ll;
        split3(xa3[j], hh, mm, ll);
        vh1[4 + j] = hh; vm1[4 + j] = mm; vl1[4 + j] = ll;
      }
      *(bf16x8*)&SA0[0 * 4096 + xrow * 32 + xc] = vh0;
      *(bf16x8*)&SA0[0 * 4096 + xrow * 32 + xc + 8] = vh1;
      *(bf16x8*)&SA0[1 * 4096 + xrow * 32 + xc] = vm0;
      *(bf16x8*)&SA0[1 * 4096 + xrow * 32 + xc + 8] = vm1;
      *(bf16x8*)&SA0[2 * 4096 + xrow * 32 + xc] = vl0;
      *(bf16x8*)&SA0[2 * 4096 + xrow * 32 + xc + 8] = vl1;
      __syncthreads();
      bf16x8 af[2][3], bfr[3][4];
#pragma unroll
      for (int i3 = 0; i3 < 3; i3++) {
#pragma unroll
        for (int i2 = 0; i2 < 2; i2++)
          af[i2][i3] = *(const bf16x8*)
              &SA0[i3 * 4096 + (w * 32 + i2 * 16 + lm) * 32 + qd * 8];
#pragma unroll
        for (int nb = 0; nb < 4; nb++)
          bfr[i3][nb] = *(const bf16x8*)
              &SB0[i3 * 2048 + (nb * 16 + lm) * 32 + qd * 8];
      }
#pragma unroll
      for (int i2 = 0; i2 < 2; i2++)
#pragma unroll
        for (int nb = 0; nb < 4; nb++) {
          f32x4 a = acc[i2][nb];
          a = mfma_bf16(af[i2][0], bfr[0][nb], a);  // hh
          a = mfma_bf16(af[i2][0], bfr[1][nb], a);  // hm
          a = mfma_bf16(af[i2][1], bfr[0][nb], a);  // mh
          a = mfma_bf16(af[i2][0], bfr[2][nb], a);  // hl
          a = mfma_bf16(af[i2][2], bfr[0][nb], a);  // lh
          a = mfma_bf16(af[i2][1], bfr[1][nb], a);  // mm
          acc[i2][nb] = a;
        }
    }
    // write fp32 partial tile (coalesced 64B runs per quad-row)
    float* Lp = Lpart + chunk * (M_ * 256);
#pragma unroll
    for (int i2 = 0; i2 < 2; i2++)
#pragma unroll
      for (int nb = 0; nb < 4; nb++)
#pragma unroll
        for (int r = 0; r < 4; r++)
          Lp[(m0 + w * 32 + i2 * 16 + qd * 4 + r) * 256 + n0 + nb * 16 + lm] =
              acc[i2][nb][r];
  }
}

// ---------------------------------------------------------------- amax
// Sum 4 K-chunk partials in FIXED order (deterministic), + bterm, argmax
// per 8-group -> qb/kb.  Block = 16 rows; thread t: row=t>>4, 16 cols.
__global__ __launch_bounds__(256) void k_amax(const float* __restrict__ Lpart,
                                              const float* __restrict__ bt,
                                              int* __restrict__ qb,
                                              int* __restrict__ kb) {
  const int t = threadIdx.x;
  const int row = blockIdx.x * 16 + (t >> 4);
  const int c0 = (t & 15) * 16;
  const float* L0 = Lpart + row * 256 + c0;
  float v[16];
#pragma unroll
  for (int c4 = 0; c4 < 16; c4 += 4) {
    f32x4 p0 = *(const f32x4*)(L0 + c4);
    f32x4 p1 = *(const f32x4*)(L0 + 1 * M_ * 256 + c4);
    f32x4 p2 = *(const f32x4*)(L0 + 2 * M_ * 256 + c4);
    f32x4 p3 = *(const f32x4*)(L0 + 3 * M_ * 256 + c4);
    f32x4 bv = *(const f32x4*)(bt + c0 + c4);
#pragma unroll
    for (int j = 0; j < 4; j++)
      v[c4 + j] = (((p0[j] + p1[j]) + p2[j]) + p3[j]) + bv[j];
  }
  const int bb = row >> 11, s = row & 2047;
#pragma unroll
  for (int g2 = 0; g2 < 2; g2++) {
    float best = v[g2 * 8];
    int bi = 0;
#pragma unroll
    for (int n = 1; n < 8; n++)
      if (v[g2 * 8 + n] > best) { best = v[g2 * 8 + n]; bi = n; }  // first-max
    int g = (c0 >> 3) + g2;           // 0..31
    int sel = g >> 4, head = g & 15;
    (sel ? kb : qb)[(bb * H_ + head) * S_ + s] = bi;
  }
}

// ---------------------------------------------------------------- bucket sort
// One block per (b,h). Stable counting sort by bucket; wave-parallel scan.
__global__ __launch_bounds__(256) void k_sort(const int* __restrict__ qb,
                                              const int* __restrict__ kb,
                                              int* __restrict__ qidx,
                                              int* __restrict__ kidx,
                                              int2* __restrict__ meta) {
  __shared__ int cnt[8][257];
  __shared__ int bst[2][9];
  __shared__ int tot[2][8];
  const int bh = blockIdx.x;
  const int t = threadIdx.x;
  const int lane = t & 63, w = t >> 6;
  for (int which = 0; which < 2; which++) {
    const int* src = (which ? kb : qb) + bh * S_;
    int* dst = (which ? kidx : qidx) + bh * QPAD;
    for (int i = t; i < QPAD; i += 256) dst[i] = -1;
    int vals[8];
    int lc[8] = {0, 0, 0, 0, 0, 0, 0, 0};
#pragma unroll
    for (int j = 0; j < 8; j++) { int b = src[t * 8 + j]; vals[j] = b; lc[b]++; }
#pragma unroll
    for (int b = 0; b < 8; b++) cnt[b][t] = lc[b];
    __syncthreads();
    // wave-parallel exclusive scan over 256 thread-slots, 2 buckets/wave
    for (int bb = w; bb < 8; bb += 4) {
      int carry = 0;
      for (int round = 0; round < 4; round++) {
        int v = cnt[bb][round * 64 + lane];
        int inc = v;
#pragma unroll
        for (int off = 1; off < 64; off <<= 1) {
          int u = __shfl_up(inc, off);
          if (lane >= off) inc += u;
        }
        cnt[bb][round * 64 + lane] = carry + inc - v;
        carry += __shfl(inc, 63);
      }
      if (lane == 0) tot[which][bb] = carry;
    }
    __syncthreads();
    if (t == 0) {
      int pos = 0;
      for (int b = 0; b < 8; b++) {
        bst[which][b] = pos;
        pos += (tot[which][b] + 63) & ~63;
      }
      bst[which][8] = pos;
    }
    __syncthreads();
    int run2[8] = {0, 0, 0, 0, 0, 0, 0, 0};
#pragma unroll
    for (int j = 0; j < 8; j++) {
      int b = vals[j];
      int pos = bst[which][b] + cnt[b][t] + run2[b]++;
      dst[pos] = t * 8 + j;
    }
    __syncthreads();
  }
  if (t == 0) {
    for (int tt = 0; tt < NQT; tt++) meta[bh * NQT + tt] = make_int2(0, 0);
    for (int b = 0; b < 8; b++) {
      int t0 = bst[0][b] >> 6;
      int nt = ((tot[0][b] + 63) & ~63) >> 6;
      int ks = bst[1][b];
      int nkt = (tot[1][b] + 63) >> 6;
      for (int tt = t0; tt < t0 + nt; tt++)
        meta[bh * NQT + tt] = make_int2(ks, nkt);
    }
  }
}

// ---------------------------------------------------------------- attention
// Bucket-sorted flash attention, double-buffered K/V. Block = (q-tile,h,b).
// One barrier per key-tile: next-tile gathers are issued into registers at
// loop top (overlap compute), written to the OTHER LDS buffer after PV.
// P-relayout LDS region is wave-private (rows w*16..w*16+15) -> no barrier.
__global__ __launch_bounds__(256) void k_attn(const bf16* __restrict__ Q,
                                              const bf16* __restrict__ K,
                                              const bf16* __restrict__ V,
                                              const int* __restrict__ qidx,
                                              const int* __restrict__ kidx,
                                              const int2* __restrict__ meta,
                                              bf16* __restrict__ O) {
  constexpr int LDK = 72;  // 144B row stride: 16B-aligned, 2-way (free)
  __shared__ bf16 Kl[2][64 * LDK];
  __shared__ bf16 Vl[2][64 * LDK];   // [dim][key]
  __shared__ bf16 Pl[64 * LDK];
  __shared__ int kbl[2][64];
  __shared__ int qsl[64];
  const int t = threadIdx.x;
  const int qt = blockIdx.x, h = blockIdx.y, b = blockIdx.z;
  const int lane = t & 63, w = t >> 6;
  const int lm = lane & 15, qd = lane >> 4;
  const int bh = b * H_ + h;

  const int2 mt = meta[bh * NQT + qt];
  const int kstart = mt.x, nkt = mt.y;

  if (t < 64) qsl[t] = qidx[bh * QPAD + qt * 64 + t];
  __syncthreads();

  if (nkt == 0) {
#pragma unroll
    for (int r = 0; r < 4; r++) {
      int qs = qsl[w * 16 + qd * 4 + r];
      if (qs >= 0)
#pragma unroll
        for (int nb = 0; nb < 4; nb++)
          O[((b * S_ + qs) * H_ + h) * DK_ + nb * 16 + lm] = (bf16)0.f;
    }
    return;
  }

  int qrow = qsl[w * 16 + lm];
  const bf16* Qp = Q + (bh * S_ + (qrow < 0 ? 0 : qrow)) * DK_;
  bf16x8 qf0 = *(const bf16x8*)(Qp + qd * 8);
  bf16x8 qf1 = *(const bf16x8*)(Qp + 32 + qd * 8);

  f32x4 oacc[4];
  float mrun[4], lrun[4];
#pragma unroll
  for (int nb = 0; nb < 4; nb++) oacc[nb] = zero4();
#pragma unroll
  for (int r = 0; r < 4; r++) { mrun[r] = -1e30f; lrun[r] = 0.f; }

  const bf16* Kbase = K + bh * S_ * DK_;
  const bf16* Vbase = V + bh * S_ * DK_;
  const int* kix = kidx + bh * QPAD + kstart;

  // staging geometry (per thread, 2 segments each for K and V)
  const int krow0 = t >> 3, ksg = t & 7;          // K: row, 16B seg
  const int krow1 = (t + 256) >> 3;
  const int vrow0 = t & 63, vsg0 = t >> 6;        // V: key, 16B dim-seg
  const int vsg1 = vsg0 + 4;

  // prologue: stage tile 0 into buffer 0
  {
    if (t < 64) kbl[0][t] = kix[t];
    int ki0 = kix[krow0]; ki0 = ki0 < 0 ? 0 : ki0;
    int ki1 = kix[krow1]; ki1 = ki1 < 0 ? 0 : ki1;
    *(bf16x8*)&Kl[0][krow0 * LDK + ksg * 8] =
        *(const bf16x8*)&Kbase[ki0 * DK_ + ksg * 8];
    *(bf16x8*)&Kl[0][krow1 * LDK + ksg * 8] =
        *(const bf16x8*)&Kbase[ki1 * DK_ + ksg * 8];
    int kv = kix[vrow0]; kv = kv < 0 ? 0 : kv;
    bf16x8 v0 = *(const bf16x8*)&Vbase[kv * DK_ + vsg0 * 8];
    bf16x8 v1 = *(const bf16x8*)&Vbase[kv * DK_ + vsg1 * 8];
#pragma unroll
    for (int j = 0; j < 8; j++) {
      Vl[0][(vsg0 * 8 + j) * LDK + vrow0] = v0[j];
      Vl[0][(vsg1 * 8 + j) * LDK + vrow0] = v1[j];
    }
  }
  __syncthreads();

  for (int kt = 0; kt < nkt; kt++) {
    const int cur = kt & 1, nxt = cur ^ 1;
    const bool more = (kt + 1 < nkt);
    // issue next-tile gathers into registers (overlaps with compute below)
    bf16x8 kn0, kn1, vn0, vn1;
    int kbn = 0;
    if (more) {
      const int kt1 = (kt + 1) * 64;
      if (t < 64) kbn = kix[kt1 + t];
      int ki0 = kix[kt1 + krow0]; ki0 = ki0 < 0 ? 0 : ki0;
      int ki1 = kix[kt1 + krow1]; ki1 = ki1 < 0 ? 0 : ki1;
      kn0 = *(const bf16x8*)&Kbase[ki0 * DK_ + ksg * 8];
      kn1 = *(const bf16x8*)&Kbase[ki1 * DK_ + ksg * 8];
      int kv = kix[kt1 + vrow0]; kv = kv < 0 ? 0 : kv;
      vn0 = *(const bf16x8*)&Vbase[kv * DK_ + vsg0 * 8];
      vn1 = *(const bf16x8*)&Vbase[kv * DK_ + vsg1 * 8];
    }

    // scores 16x64 per wave (C-layout: row=qd*4+r, col=nb*16+lm)
    f32x4 sc[4];
#pragma unroll
    for (int nb = 0; nb < 4; nb++) {
      bf16x8 kf0 = *(const bf16x8*)&Kl[cur][(nb * 16 + lm) * LDK + qd * 8];
      bf16x8 kf1 = *(const bf16x8*)&Kl[cur][(nb * 16 + lm) * LDK + 32 + qd * 8];
      f32x4 z = zero4();
      z = mfma_bf16(qf0, kf0, z);
      z = mfma_bf16(qf1, kf1, z);
      sc[nb] = z;
    }
    // sentinel slots (bucket padding) -> masked (Q already prescaled 1/8)
#pragma unroll
    for (int nb = 0; nb < 4; nb++) {
      bool valid = kbl[cur][nb * 16 + lm] >= 0;
#pragma unroll
      for (int r = 0; r < 4; r++)
        sc[nb][r] = valid ? sc[nb][r] : -1e30f;
    }
    float mnew[4], alpha[4], rs[4];
#pragma unroll
    for (int r = 0; r < 4; r++) {
      float tm = fmaxf(fmaxf(sc[0][r], sc[1][r]), fmaxf(sc[2][r], sc[3][r]));
      tm = fmaxf(tm, __shfl_xor(tm, 1));
      tm = fmaxf(tm, __shfl_xor(tm, 2));
      tm = fmaxf(tm, __shfl_xor(tm, 4));
      tm = fmaxf(tm, __shfl_xor(tm, 8));
      mnew[r] = fmaxf(mrun[r], tm);
      alpha[r] = __expf(mrun[r] - mnew[r]);
      mrun[r] = mnew[r];
      rs[r] = 0.f;
    }
#pragma unroll
    for (int nb = 0; nb < 4; nb++)
#pragma unroll
      for (int r = 0; r < 4; r++) {
        float p = (sc[nb][r] > -1e29f) ? __expf(sc[nb][r] - mnew[r]) : 0.f;
        sc[nb][r] = p;
        rs[r] += p;
      }
#pragma unroll
    for (int r = 0; r < 4; r++) {
      float s = rs[r];
      s += __shfl_xor(s, 1);
      s += __shfl_xor(s, 2);
      s += __shfl_xor(s, 4);
      s += __shfl_xor(s, 8);
      lrun[r] = lrun[r] * alpha[r] + s;
    }
#pragma unroll
    for (int nb = 0; nb < 4; nb++)
#pragma unroll
      for (int r = 0; r < 4; r++) oacc[nb][r] *= alpha[r];
    // P: C-layout -> A-layout via wave-private LDS rows (no barrier needed)
#pragma unroll
    for (int nb = 0; nb < 4; nb++)
#pragma unroll
      for (int r = 0; r < 4; r++)
        Pl[(w * 16 + qd * 4 + r) * LDK + nb * 16 + lm] = (bf16)sc[nb][r];
    bf16x8 pa0 = *(const bf16x8*)&Pl[(w * 16 + lm) * LDK + qd * 8];
    bf16x8 pa1 = *(const bf16x8*)&Pl[(w * 16 + lm) * LDK + 32 + qd * 8];
#pragma unroll
    for (int nb = 0; nb < 4; nb++) {
      bf16x8 vf0 = *(const bf16x8*)&Vl[cur][(nb * 16 + lm) * LDK + qd * 8];
      bf16x8 vf1 = *(const bf16x8*)&Vl[cur][(nb * 16 + lm) * LDK + 32 + qd * 8];
      oacc[nb] = mfma_bf16(pa0, vf0, oacc[nb]);
      oacc[nb] = mfma_bf16(pa1, vf1, oacc[nb]);
    }
    // commit next tile to the other buffer, then one barrier
    if (more) {
      if (t < 64) kbl[nxt][t] = kbn;
      *(bf16x8*)&Kl[nxt][krow0 * LDK + ksg * 8] = kn0;
      *(bf16x8*)&Kl[nxt][krow1 * LDK + ksg * 8] = kn1;
#pragma unroll
      for (int j = 0; j < 8; j++) {
        Vl[nxt][(vsg0 * 8 + j) * LDK + vrow0] = vn0[j];
        Vl[nxt][(vsg1 * 8 + j) * LDK + vrow0] = vn1[j];
      }
      __syncthreads();
    }
  }
  // epilogue: scatter O rows back to original positions
#pragma unroll
  for (int r = 0; r < 4; r++) {
    int qs = qsl[w * 16 + qd * 4 + r];
    if (qs < 0) continue;
    float l = lrun[r];
    float inv = (l > 0.f) ? 1.f / l : 0.f;
#pragma unroll
    for (int nb = 0; nb < 4; nb++)
      O[((b * S_ + qs) * H_ + h) * DK_ + nb * 16 + lm] = (bf16)(oacc[nb][r] * inv);
  }
}

// ---------------------------------------------------------------- out GEMM
// C[m][n] = sum_k A[m][k]*Bt[n][k] + bias[n] -> fp32; 64x128 tile (512 blocks)
__global__ __launch_bounds__(256) void k_gout(const bf16* __restrict__ A,
                                              const bf16* __restrict__ Bt,
                                              const float* __restrict__ bias,
                                              float* __restrict__ out) {
  __shared__ __align__(16) bf16 Al[64 * 32];
  __shared__ __align__(16) bf16 Bl[128 * 32];
  const int t = threadIdx.x;
  const int lane = t & 63, w = t >> 6;
  const int lm = lane & 15, qd = lane >> 4;
  const int srow = lane >> 2, sseg = lane & 3;
  const int m0 = blockIdx.x * 64, n0 = blockIdx.y * 128;
  const int wm = w >> 1, wn = w & 1;

  f32x4 acc[2][4];
#pragma unroll
  for (int i = 0; i < 2; i++)
#pragma unroll
    for (int j = 0; j < 4; j++) acc[i][j] = zero4();

  for (int k0 = 0; k0 < D_; k0 += 32) {
    __syncthreads();
    load_lds16(&A[(m0 + w * 16 + srow) * D_ + k0 + sseg * 8],
               &Al[(w * 16) * 32]);
    load_lds16(&Bt[(n0 + w * 16 + srow) * D_ + k0 + sseg * 8],
               &Bl[(w * 16) * 32]);
    load_lds16(&Bt[(n0 + 64 + w * 16 + srow) * D_ + k0 + sseg * 8],
               &Bl[(64 + w * 16) * 32]);
    __syncthreads();
    bf16x8 af[2], bfr[4];
#pragma unroll
    for (int i = 0; i < 2; i++)
      af[i] = *(const bf16x8*)&Al[(wm * 32 + i * 16 + lm) * 32 + qd * 8];
#pragma unroll
    for (int j = 0; j < 4; j++)
      bfr[j] = *(const bf16x8*)&Bl[(wn * 64 + j * 16 + lm) * 32 + qd * 8];
#pragma unroll
    for (int i = 0; i < 2; i++)
#pragma unroll
      for (int j = 0; j < 4; j++) acc[i][j] = mfma_bf16(af[i], bfr[j], acc[i][j]);
  }
#pragma unroll
  for (int j = 0; j < 4; j++) {
    int n = n0 + wn * 64 + j * 16 + lm;
    float bv = bias[n];
#pragma unroll
    for (int i = 0; i < 2; i++) {
      int mbase = m0 + wm * 32 + i * 16 + qd * 4;
#pragma unroll
      for (int r = 0; r < 4; r++)
        out[(mbase + r) * D_ + n] = acc[i][j][r] + bv;
    }
  }
}

// ---------------------------------------------------------------- launch
extern "C" void kernel_launch(void* const* d_in, const int* in_sizes, int n_in,
                              void* d_out, int out_size, void* d_ws, size_t ws_size,
                              hipStream_t stream) {
  (void)in_sizes; (void)n_in; (void)out_size; (void)ws_size;
  const float* x  = (const float*)d_in[0];
  const float* Wq = (const float*)d_in[1];
  const float* bq = (const float*)d_in[2];
  const float* Wk = (const float*)d_in[3];
  const float* bk = (const float*)d_in[4];
  const float* Wv = (const float*)d_in[5];
  const float* bv = (const float*)d_in[6];
  const float* Wo = (const float*)d_in[7];
  const float* bo = (const float*)d_in[8];
  const float* R  = (const float*)d_in[9];

  char* ws = (char*)d_ws;
  bf16*  xh   = (bf16*)(ws + 0);          // 8 MB
  bf16*  Qb   = (bf16*)(ws + 8388608);    // 8 MB  [B,H,S,DK] (prescaled 1/8)
  bf16*  Kb   = (bf16*)(ws + 16777216);   // 8 MB  [B,H,S,DK]
  bf16*  Vb   = (bf16*)(ws + 25165824);   // 8 MB  [B,H,S,DK]
  bf16*  Ob   = (bf16*)(ws + 33554432);   // 8 MB  [B,S,H,DK]
  bf16*  Wtq  = (bf16*)(ws + 41943040);   // 2 MB each
  bf16*  Wtk  = (bf16*)(ws + 44040192);
  bf16*  Wtv  = (bf16*)(ws + 46137344);
  bf16*  Wto  = (bf16*)(ws + 48234496);
  int*   qbuf = (int*)(ws + 51380224);    // 256 KB each
  int*   kbuf = (int*)(ws + 51642368);
  float* bt   = (float*)(ws + 51904512);  // 1 KB
  bf16*  Pth  = (bf16*)(ws + 51905536);   // 512 KB each
  bf16*  Ptm  = (bf16*)(ws + 52429824);
  bf16*  Ptl  = (bf16*)(ws + 52954112);
  int*   qidxp= (int*)(ws + 53478400);    // 320 KB each
  int*   kidxp= (int*)(ws + 53806080);
  int2*  meta = (int2*)(ws + 54133760);   // 10 KB
  float* Lpart= (float*)(ws + 67108864);  // [64MB,80MB): 4 x 4MB fp32 partials

  k_prep<<<dim3(16, 16, 6), dim3(256), 0, stream>>>(
      Wq, Wk, Wv, Wo, x, bq, bk, R, Wtq, Wtk, Wtv, Wto, xh,
      Pth, Ptm, Ptl, bt);

  k_main<<<dim3(32, 40), dim3(256), 0, stream>>>(
      x, xh, Wtq, Wtk, Wtv, bq, bk, bv, Pth, Ptm, Ptl, Qb, Kb, Vb, Lpart);

  k_amax<<<dim3(256), dim3(256), 0, stream>>>(Lpart, bt, qbuf, kbuf);

  k_sort<<<dim3(32), dim3(256), 0, stream>>>(qbuf, kbuf, qidxp, kidxp, meta);

  k_attn<<<dim3(NQT, H_, B_), dim3(256), 0, stream>>>(Qb, Kb, Vb, qidxp, kidxp,
                                                      meta, Ob);

  k_gout<<<dim3(64, 8), dim3(256), 0, stream>>>(Ob, Wto, bo, (float*)d_out);
}

// Round 11
// 218.230 us; speedup vs baseline: 1.0101x; 1.0101x over previous
//
#include <hip/hip_runtime.h>
#include <hip/hip_bf16.h>

// LSH Attention, MI355X gfx950.  6-dispatch pipeline:
//  1) k_prep  (z-branch): transW x4, x->bf16 cast, P=W@R^T fold + 3-split,
//     bterm
//  2) k_main  (y-branch): Q/K/V projection GEMM (m97-style 128x128,
//     global_load_lds width-16; Q prescaled by 0.125 = 1/sqrt(DK), exact)
//     + bucket-logit GEMM partials (6-term split-bf16, K-split x4, 64x64
//     tiles -- R10 showed 128x64 logit tiles LOSE 2.4us to occupancy).
//     Grid (32,56): zero dead blocks.  x sync-loaded fp32 + split3
//     in-register (R8: all-async 6-stream staging serializes LDS-DMA, -19us)
//  3) k_amax: deterministic fixed-order partial reduction + bterm + argmax
//  4) k_sort: per-(b,h) counting sort by bucket (wave-parallel prefix scan)
//  5) k_attn: bucket-sorted flash attention, double-buffered K/V (1 barrier
//     per tile; P-relayout is wave-private so needs no barrier)
//  6) k_gout: output GEMM 64x128 tiles -> fp32 d_out
//
// MFMA 16x16x32 bf16 layouts (verified in guide):
//  A: lane holds A[m=lane&15][k=(lane>>4)*8+j]
//  B: lane holds B[k=(lane>>4)*8+j][n=lane&15]
//  C/D: lane holds D[m=(lane>>4)*4+r][n=lane&15]

typedef __bf16 bf16;
typedef __bf16 bf16x8 __attribute__((ext_vector_type(8)));
typedef __bf16 bf16x4 __attribute__((ext_vector_type(4)));
typedef float f32x4 __attribute__((ext_vector_type(4)));

#define DEV static __device__ __forceinline__

DEV f32x4 zero4() { f32x4 z; z[0]=0.f; z[1]=0.f; z[2]=0.f; z[3]=0.f; return z; }

DEV f32x4 mfma_bf16(bf16x8 a, bf16x8 b, f32x4 c) {
  return __builtin_amdgcn_mfma_f32_16x16x32_bf16(a, b, c, 0, 0, 0);
}

// async global->LDS, 16B/lane; LDS dest = wave-uniform base + lane*16
DEV void load_lds16(const bf16* g, bf16* l) {
  __builtin_amdgcn_global_load_lds(
      (const __attribute__((address_space(1))) void*)g,
      (__attribute__((address_space(3))) void*)l, 16, 0, 0);
}

DEV void split3(float f, bf16& h, bf16& m, bf16& l) {
  h = (bf16)f;
  float rm = f - (float)h;
  m = (bf16)rm;
  l = (bf16)(rm - (float)m);
}

#define B_  2
#define S_  2048
#define D_  1024
#define H_  16
#define NH_ 8
#define DK_ 64
#define M_  4096   // B_*S_
#define QPAD 2560  // 2048 + 8*64 (per-bucket 64-alignment padding)
#define NQT  40    // max q-tiles per (b,h): 32 + 8

// ---------------------------------------------------------------- prep
// z<4: transW (64x64 transpose+cast); z=4: x->bf16; z=5 (64 blocks):
// P[d][c]=W(:,h*64:)@R[n]^T fold, 3-split transposed write, + bterm.
__global__ __launch_bounds__(256) void k_prep(
    const float* __restrict__ Wq, const float* __restrict__ Wk,
    const float* __restrict__ Wv, const float* __restrict__ Wo,
    const float* __restrict__ x, const float* __restrict__ bq,
    const float* __restrict__ bk, const float* __restrict__ R,
    bf16* __restrict__ Wtq, bf16* __restrict__ Wtk,
    bf16* __restrict__ Wtv, bf16* __restrict__ Wto,
    bf16* __restrict__ xh, bf16* __restrict__ Pth, bf16* __restrict__ Ptm,
    bf16* __restrict__ Ptl, float* __restrict__ bt) {
  __shared__ float tile[64][65];
  __shared__ float Rl[512];
  const int t = threadIdx.x;
  const int z = blockIdx.z;
  if (z < 4) {
    const float* W = z == 0 ? Wq : z == 1 ? Wk : z == 2 ? Wv : Wo;
    bf16* Wt = z == 0 ? Wtq : z == 1 ? Wtk : z == 2 ? Wtv : Wto;
    int k0 = blockIdx.x * 64, n0 = blockIdx.y * 64;
    int c = t & 63, r4 = t >> 6;
#pragma unroll
    for (int i = 0; i < 16; i++) {
      int r = r4 * 16 + i;
      tile[r][c] = W[(k0 + r) * D_ + n0 + c];
    }
    __syncthreads();
#pragma unroll
    for (int i = 0; i < 16; i++) {
      int r = r4 * 16 + i;
      Wt[(n0 + r) * D_ + k0 + c] = (bf16)tile[c][r];
    }
  } else if (z == 4) {
    int bid = blockIdx.y * 16 + blockIdx.x;
    int base = bid * 16384 + t * 4;
#pragma unroll 4
    for (int it = 0; it < 16; it++) {
      int i = base + it * 1024;
      f32x4 v = *(const f32x4*)(x + i);
      bf16x4 o;
#pragma unroll
      for (int j = 0; j < 4; j++) o[j] = (bf16)v[j];
      *(bf16x4*)(xh + i) = o;
    }
  } else {
    int bid = blockIdx.y * 16 + blockIdx.x;
    if (bid >= 64) return;
    Rl[t] = R[t];
    Rl[t + 256] = R[t + 256];
    __syncthreads();
    const int d0 = bid * 16;
    const int sel = t >> 7, hn = t & 127, h = hn >> 3, n = hn & 7;
    const float* W = sel ? Wk : Wq;
    const float* Rr = &Rl[n * 64];
    bf16x8 vh[2], vm[2], vl[2];
#pragma unroll
    for (int dl = 0; dl < 16; dl++) {
      const float* wr = W + (d0 + dl) * D_ + h * 64;
      float acc = 0.f;
#pragma unroll
      for (int k = 0; k < 64; k += 4) {
        f32x4 wv = *(const f32x4*)(wr + k);
        acc += (wv[0] * Rr[k] + wv[1] * Rr[k + 1]) +
               (wv[2] * Rr[k + 2] + wv[3] * Rr[k + 3]);
      }
      bf16 hh, mm, ll;
      split3(acc, hh, mm, ll);
      vh[dl >> 3][dl & 7] = hh;
      vm[dl >> 3][dl & 7] = mm;
      vl[dl >> 3][dl & 7] = ll;
    }
    *(bf16x8*)&Pth[t * D_ + d0] = vh[0];
    *(bf16x8*)&Pth[t * D_ + d0 + 8] = vh[1];
    *(bf16x8*)&Ptm[t * D_ + d0] = vm[0];
    *(bf16x8*)&Ptm[t * D_ + d0 + 8] = vm[1];
    *(bf16x8*)&Ptl[t * D_ + d0] = vl[0];
    *(bf16x8*)&Ptl[t * D_ + d0 + 8] = vl[1];
    if (bid == 0) {
      const float* bb = sel ? bk : bq;
      float acc = 0.f;
#pragma unroll 8
      for (int k = 0; k < 64; k++) acc += bb[h * 64 + k] * Rr[k];
      bt[t] = acc;
    }
  }
}

// ---------------------------------------------------------------- main fused
// grid (32, 56).  y<24: QKV projection GEMM, 128x128 tile, mat=y>>3,
// n0=(y&7)*128, m0=x*128.  Q (mat 0) prescaled by 0.125 (exact pow2).
// y in 24..55: bucket-logit GEMM partial, yy=y-24: chunk=yy>>3, sub=yy&7,
// n0=(sub&3)*64, m0=(x + (sub>>2)*32)*64 (64x64 tile -- R9's measured-best),
// K in [chunk*256,+256): 6-term split-bf16, x sync-loaded fp32 + in-register
// split3 overlapping 3 async P streams, fp32 partial -> Lpart[chunk].
__global__ __launch_bounds__(256) void k_main(
    const float* __restrict__ x, const bf16* __restrict__ xh,
    const bf16* __restrict__ Wtq, const bf16* __restrict__ Wtk,
    const bf16* __restrict__ Wtv, const float* __restrict__ bq,
    const float* __restrict__ bk, const float* __restrict__ bv,
    const bf16* __restrict__ Pth, const bf16* __restrict__ Ptm,
    const bf16* __restrict__ Ptl,
    bf16* __restrict__ Qb, bf16* __restrict__ Kb, bf16* __restrict__ Vb,
    float* __restrict__ Lpart) {
  __shared__ __align__(16) bf16 SA[3][2048];
  __shared__ __align__(16) bf16 SB[3][2048];
  const int t = threadIdx.x;
  const int lane = t & 63, w = t >> 6;
  const int lm = lane & 15, qd = lane >> 4;
  const int srow = lane >> 2, sseg = lane & 3;  // 16 rows x 4 segs per instr

  if (blockIdx.y < 24) {  // ---------------- QKV GEMM
    bf16* Al = &SA[0][0];  // 128x32 contiguous
    bf16* Bl = &SB[0][0];
    const int m0 = blockIdx.x * 128;
    const int mat = blockIdx.y >> 3;
    const int n0 = (blockIdx.y & 7) * 128;
    const bf16* Bt = mat == 0 ? Wtq : (mat == 1 ? Wtk : Wtv);
    const float* bias = mat == 0 ? bq : (mat == 1 ? bk : bv);
    bf16* out = mat == 0 ? Qb : (mat == 1 ? Kb : Vb);
    const float osc = mat == 0 ? 0.125f : 1.f;  // fold 1/sqrt(DK) into Q
    const int wm = w >> 1, wn = w & 1;

    f32x4 acc[4][4];
#pragma unroll
    for (int i = 0; i < 4; i++)
#pragma unroll
      for (int j = 0; j < 4; j++) acc[i][j] = zero4();

    for (int k0 = 0; k0 < D_; k0 += 32) {
      __syncthreads();
      load_lds16(&xh[(m0 + w * 16 + srow) * D_ + k0 + sseg * 8],
                 &Al[(w * 16) * 32]);
      load_lds16(&xh[(m0 + 64 + w * 16 + srow) * D_ + k0 + sseg * 8],
                 &Al[(64 + w * 16) * 32]);
      load_lds16(&Bt[(n0 + w * 16 + srow) * D_ + k0 + sseg * 8],
                 &Bl[(w * 16) * 32]);
      load_lds16(&Bt[(n0 + 64 + w * 16 + srow) * D_ + k0 + sseg * 8],
                 &Bl[(64 + w * 16) * 32]);
      __syncthreads();
      bf16x8 af[4], bfr[4];
#pragma unroll
      for (int i = 0; i < 4; i++)
        af[i] = *(const bf16x8*)&Al[(wm * 64 + i * 16 + lm) * 32 + qd * 8];
#pragma unroll
      for (int j = 0; j < 4; j++)
        bfr[j] = *(const bf16x8*)&Bl[(wn * 64 + j * 16 + lm) * 32 + qd * 8];
#pragma unroll
      for (int i = 0; i < 4; i++)
#pragma unroll
        for (int j = 0; j < 4; j++)
          acc[i][j] = mfma_bf16(af[i], bfr[j], acc[i][j]);
    }
#pragma unroll
    for (int j = 0; j < 4; j++) {
      int n = n0 + wn * 64 + j * 16 + lm;
      float bv2 = bias[n];
#pragma unroll
      for (int i = 0; i < 4; i++) {
        int mbase = m0 + wm * 64 + i * 16 + qd * 4;
#pragma unroll
        for (int r = 0; r < 4; r++) {
          int m = mbase + r;
          int bb = m >> 11, s = m & 2047, hh = n >> 6, d = n & 63;
          out[((bb * H_ + hh) * S_ + s) * DK_ + d] =
              (bf16)((acc[i][j][r] + bv2) * osc);
        }
      }
    }
  } else {  // ---------------- bucket-logit GEMM partial (K-split x4)
    const int yy = blockIdx.y - 24;
    const int chunk = yy >> 3, sub = yy & 7;
    const int m0 = (blockIdx.x + (sub >> 2) * 32) * 64;
    const int n0 = (sub & 3) * 64;
    f32x4 acc[4];
#pragma unroll
    for (int nb = 0; nb < 4; nb++) acc[nb] = zero4();
    const int xrow = t >> 2, xc8 = (t & 3) * 8;
    const int kbeg = chunk * 256, kend = kbeg + 256;

    for (int k0 = kbeg; k0 < kend; k0 += 32) {
      __syncthreads();
      // x fp32 -> 3-way bf16 split in-register -> LDS (overlaps async below)
      f32x4 xa = *(const f32x4*)&x[(m0 + xrow) * D_ + k0 + xc8];
      f32x4 xb2 = *(const f32x4*)&x[(m0 + xrow) * D_ + k0 + xc8 + 4];
      // P splits: async, wave w stages quarter w of each array
      load_lds16(&Pth[(n0 + w * 16 + srow) * D_ + k0 + sseg * 8],
                 &SB[0][(w * 16) * 32]);
      load_lds16(&Ptm[(n0 + w * 16 + srow) * D_ + k0 + sseg * 8],
                 &SB[1][(w * 16) * 32]);
      load_lds16(&Ptl[(n0 + w * 16 + srow) * D_ + k0 + sseg * 8],
                 &SB[2][(w * 16) * 32]);
      bf16x8 vh, vm, vl;
#pragma unroll
      for (int j = 0; j < 4; j++) {
        bf16 hh, mm, ll;
        split3(xa[j], hh, mm, ll);
        vh[j] = hh; vm[j] = mm; vl[j] = ll;
        split3(xb2[j], hh, mm, ll);
        vh[4 + j] = hh; vm[4 + j] = mm; vl[4 + j] = ll;
      }
      *(bf16x8*)&SA[0][xrow * 32 + xc8] = vh;
      *(bf16x8*)&SA[1][xrow * 32 + xc8] = vm;
      *(bf16x8*)&SA[2][xrow * 32 + xc8] = vl;
      __syncthreads();
      bf16x8 af[3], bfr[3][4];
#pragma unroll
      for (int i3 = 0; i3 < 3; i3++) {
        af[i3] = *(const bf16x8*)&SA[i3][(w * 16 + lm) * 32 + qd * 8];
#pragma unroll
        for (int nb = 0; nb < 4; nb++)
          bfr[i3][nb] = *(const bf16x8*)&SB[i3][(nb * 16 + lm) * 32 + qd * 8];
      }
#pragma unroll
      for (int nb = 0; nb < 4; nb++) {
        f32x4 a = acc[nb];
        a = mfma_bf16(af[0], bfr[0][nb], a);  // hh
        a = mfma_bf16(af[0], bfr[1][nb], a);  // hm
        a = mfma_bf16(af[1], bfr[0][nb], a);  // mh
        a = mfma_bf16(af[0], bfr[2][nb], a);  // hl
        a = mfma_bf16(af[2], bfr[0][nb], a);  // lh
        a = mfma_bf16(af[1], bfr[1][nb], a);  // mm
        acc[nb] = a;
      }
    }
    // write fp32 partial tile (coalesced 64B runs per quad-row)
    float* Lp = Lpart + chunk * (M_ * 256);
#pragma unroll
    for (int nb = 0; nb < 4; nb++)
#pragma unroll
      for (int r = 0; r < 4; r++)
        Lp[(m0 + w * 16 + qd * 4 + r) * 256 + n0 + nb * 16 + lm] = acc[nb][r];
  }
}

// ---------------------------------------------------------------- amax
// Sum 4 K-chunk partials in FIXED order (deterministic), + bterm, argmax
// per 8-group -> qb/kb.  Block = 16 rows; thread t: row=t>>4, 16 cols.
__global__ __launch_bounds__(256) void k_amax(const float* __restrict__ Lpart,
                                              const float* __restrict__ bt,
                                              int* __restrict__ qb,
                                              int* __restrict__ kb) {
  const int t = threadIdx.x;
  const int row = blockIdx.x * 16 + (t >> 4);
  const int c0 = (t & 15) * 16;
  const float* L0 = Lpart + row * 256 + c0;
  float v[16];
#pragma unroll
  for (int c4 = 0; c4 < 16; c4 += 4) {
    f32x4 p0 = *(const f32x4*)(L0 + c4);
    f32x4 p1 = *(const f32x4*)(L0 + 1 * M_ * 256 + c4);
    f32x4 p2 = *(const f32x4*)(L0 + 2 * M_ * 256 + c4);
    f32x4 p3 = *(const f32x4*)(L0 + 3 * M_ * 256 + c4);
    f32x4 bv = *(const f32x4*)(bt + c0 + c4);
#pragma unroll
    for (int j = 0; j < 4; j++)
      v[c4 + j] = (((p0[j] + p1[j]) + p2[j]) + p3[j]) + bv[j];
  }
  const int bb = row >> 11, s = row & 2047;
#pragma unroll
  for (int g2 = 0; g2 < 2; g2++) {
    float best = v[g2 * 8];
    int bi = 0;
#pragma unroll
    for (int n = 1; n < 8; n++)
      if (v[g2 * 8 + n] > best) { best = v[g2 * 8 + n]; bi = n; }  // first-max
    int g = (c0 >> 3) + g2;           // 0..31
    int sel = g >> 4, head = g & 15;
    (sel ? kb : qb)[(bb * H_ + head) * S_ + s] = bi;
  }
}

// ---------------------------------------------------------------- bucket sort
// One block per (b,h). Stable counting sort by bucket; wave-parallel scan.
__global__ __launch_bounds__(256) void k_sort(const int* __restrict__ qb,
                                              const int* __restrict__ kb,
                                              int* __restrict__ qidx,
                                              int* __restrict__ kidx,
                                              int2* __restrict__ meta) {
  __shared__ int cnt[8][257];
  __shared__ int bst[2][9];
  __shared__ int tot[2][8];
  const int bh = blockIdx.x;
  const int t = threadIdx.x;
  const int lane = t & 63, w = t >> 6;
  for (int which = 0; which < 2; which++) {
    const int* src = (which ? kb : qb) + bh * S_;
    int* dst = (which ? kidx : qidx) + bh * QPAD;
    for (int i = t; i < QPAD; i += 256) dst[i] = -1;
    int vals[8];
    int lc[8] = {0, 0, 0, 0, 0, 0, 0, 0};
#pragma unroll
    for (int j = 0; j < 8; j++) { int b = src[t * 8 + j]; vals[j] = b; lc[b]++; }
#pragma unroll
    for (int b = 0; b < 8; b++) cnt[b][t] = lc[b];
    __syncthreads();
    // wave-parallel exclusive scan over 256 thread-slots, 2 buckets/wave
    for (int bb = w; bb < 8; bb += 4) {
      int carry = 0;
      for (int round = 0; round < 4; round++) {
        int v = cnt[bb][round * 64 + lane];
        int inc = v;
#pragma unroll
        for (int off = 1; off < 64; off <<= 1) {
          int u = __shfl_up(inc, off);
          if (lane >= off) inc += u;
        }
        cnt[bb][round * 64 + lane] = carry + inc - v;
        carry += __shfl(inc, 63);
      }
      if (lane == 0) tot[which][bb] = carry;
    }
    __syncthreads();
    if (t == 0) {
      int pos = 0;
      for (int b = 0; b < 8; b++) {
        bst[which][b] = pos;
        pos += (tot[which][b] + 63) & ~63;
      }
      bst[which][8] = pos;
    }
    __syncthreads();
    int run2[8] = {0, 0, 0, 0, 0, 0, 0, 0};
#pragma unroll
    for (int j = 0; j < 8; j++) {
      int b = vals[j];
      int pos = bst[which][b] + cnt[b][t] + run2[b]++;
      dst[pos] = t * 8 + j;
    }
    __syncthreads();
  }
  if (t == 0) {
    for (int tt = 0; tt < NQT; tt++) meta[bh * NQT + tt] = make_int2(0, 0);
    for (int b = 0; b < 8; b++) {
      int t0 = bst[0][b] >> 6;
      int nt = ((tot[0][b] + 63) & ~63) >> 6;
      int ks = bst[1][b];
      int nkt = (tot[1][b] + 63) >> 6;
      for (int tt = t0; tt < t0 + nt; tt++)
        meta[bh * NQT + tt] = make_int2(ks, nkt);
    }
  }
}

// ---------------------------------------------------------------- attention
// Bucket-sorted flash attention, double-buffered K/V. Block = (q-tile,h,b).
// One barrier per key-tile: next-tile gathers are issued into registers at
// loop top (overlap compute), written to the OTHER LDS buffer after PV.
// P-relayout LDS region is wave-private (rows w*16..w*16+15) -> no barrier.
__global__ __launch_bounds__(256) void k_attn(const bf16* __restrict__ Q,
                                              const bf16* __restrict__ K,
                                              const bf16* __restrict__ V,
                                              const int* __restrict__ qidx,
                                              const int* __restrict__ kidx,
                                              const int2* __restrict__ meta,
                                              bf16* __restrict__ O) {
  constexpr int LDK = 72;  // 144B row stride: 16B-aligned, 2-way (free)
  __shared__ bf16 Kl[2][64 * LDK];
  __shared__ bf16 Vl[2][64 * LDK];   // [dim][key]
  __shared__ bf16 Pl[64 * LDK];
  __shared__ int kbl[2][64];
  __shared__ int qsl[64];
  const int t = threadIdx.x;
  const int qt = blockIdx.x, h = blockIdx.y, b = blockIdx.z;
  const int lane = t & 63, w = t >> 6;
  const int lm = lane & 15, qd = lane >> 4;
  const int bh = b * H_ + h;

  const int2 mt = meta[bh * NQT + qt];
  const int kstart = mt.x, nkt = mt.y;

  if (t < 64) qsl[t] = qidx[bh * QPAD + qt * 64 + t];
  __syncthreads();

  if (nkt == 0) {
#pragma unroll
    for (int r = 0; r < 4; r++) {
      int qs = qsl[w * 16 + qd * 4 + r];
      if (qs >= 0)
#pragma unroll
        for (int nb = 0; nb < 4; nb++)
          O[((b * S_ + qs) * H_ + h) * DK_ + nb * 16 + lm] = (bf16)0.f;
    }
    return;
  }

  int qrow = qsl[w * 16 + lm];
  const bf16* Qp = Q + (bh * S_ + (qrow < 0 ? 0 : qrow)) * DK_;
  bf16x8 qf0 = *(const bf16x8*)(Qp + qd * 8);
  bf16x8 qf1 = *(const bf16x8*)(Qp + 32 + qd * 8);

  f32x4 oacc[4];
  float mrun[4], lrun[4];
#pragma unroll
  for (int nb = 0; nb < 4; nb++) oacc[nb] = zero4();
#pragma unroll
  for (int r = 0; r < 4; r++) { mrun[r] = -1e30f; lrun[r] = 0.f; }

  const bf16* Kbase = K + bh * S_ * DK_;
  const bf16* Vbase = V + bh * S_ * DK_;
  const int* kix = kidx + bh * QPAD + kstart;

  // staging geometry (per thread, 2 segments each for K and V)
  const int krow0 = t >> 3, ksg = t & 7;          // K: row, 16B seg
  const int krow1 = (t + 256) >> 3;
  const int vrow0 = t & 63, vsg0 = t >> 6;        // V: key, 16B dim-seg
  const int vsg1 = vsg0 + 4;

  // prologue: stage tile 0 into buffer 0
  {
    if (t < 64) kbl[0][t] = kix[t];
    int ki0 = kix[krow0]; ki0 = ki0 < 0 ? 0 : ki0;
    int ki1 = kix[krow1]; ki1 = ki1 < 0 ? 0 : ki1;
    *(bf16x8*)&Kl[0][krow0 * LDK + ksg * 8] =
        *(const bf16x8*)&Kbase[ki0 * DK_ + ksg * 8];
    *(bf16x8*)&Kl[0][krow1 * LDK + ksg * 8] =
        *(const bf16x8*)&Kbase[ki1 * DK_ + ksg * 8];
    int kv = kix[vrow0]; kv = kv < 0 ? 0 : kv;
    bf16x8 v0 = *(const bf16x8*)&Vbase[kv * DK_ + vsg0 * 8];
    bf16x8 v1 = *(const bf16x8*)&Vbase[kv * DK_ + vsg1 * 8];
#pragma unroll
    for (int j = 0; j < 8; j++) {
      Vl[0][(vsg0 * 8 + j) * LDK + vrow0] = v0[j];
      Vl[0][(vsg1 * 8 + j) * LDK + vrow0] = v1[j];
    }
  }
  __syncthreads();

  for (int kt = 0; kt < nkt; kt++) {
    const int cur = kt & 1, nxt = cur ^ 1;
    const bool more = (kt + 1 < nkt);
    // issue next-tile gathers into registers (overlaps with compute below)
    bf16x8 kn0, kn1, vn0, vn1;
    int kbn = 0;
    if (more) {
      const int kt1 = (kt + 1) * 64;
      if (t < 64) kbn = kix[kt1 + t];
      int ki0 = kix[kt1 + krow0]; ki0 = ki0 < 0 ? 0 : ki0;
      int ki1 = kix[kt1 + krow1]; ki1 = ki1 < 0 ? 0 : ki1;
      kn0 = *(const bf16x8*)&Kbase[ki0 * DK_ + ksg * 8];
      kn1 = *(const bf16x8*)&Kbase[ki1 * DK_ + ksg * 8];
      int kv = kix[kt1 + vrow0]; kv = kv < 0 ? 0 : kv;
      vn0 = *(const bf16x8*)&Vbase[kv * DK_ + vsg0 * 8];
      vn1 = *(const bf16x8*)&Vbase[kv * DK_ + vsg1 * 8];
    }

    // scores 16x64 per wave (C-layout: row=qd*4+r, col=nb*16+lm)
    f32x4 sc[4];
#pragma unroll
    for (int nb = 0; nb < 4; nb++) {
      bf16x8 kf0 = *(const bf16x8*)&Kl[cur][(nb * 16 + lm) * LDK + qd * 8];
      bf16x8 kf1 = *(const bf16x8*)&Kl[cur][(nb * 16 + lm) * LDK + 32 + qd * 8];
      f32x4 z = zero4();
      z = mfma_bf16(qf0, kf0, z);
      z = mfma_bf16(qf1, kf1, z);
      sc[nb] = z;
    }
    // sentinel slots (bucket padding) -> masked (Q already prescaled 1/8)
#pragma unroll
    for (int nb = 0; nb < 4; nb++) {
      bool valid = kbl[cur][nb * 16 + lm] >= 0;
#pragma unroll
      for (int r = 0; r < 4; r++)
        sc[nb][r] = valid ? sc[nb][r] : -1e30f;
    }
    float mnew[4], alpha[4], rs[4];
#pragma unroll
    for (int r = 0; r < 4; r++) {
      float tm = fmaxf(fmaxf(sc[0][r], sc[1][r]), fmaxf(sc[2][r], sc[3][r]));
      tm = fmaxf(tm, __shfl_xor(tm, 1));
      tm = fmaxf(tm, __shfl_xor(tm, 2));
      tm = fmaxf(tm, __shfl_xor(tm, 4));
      tm = fmaxf(tm, __shfl_xor(tm, 8));
      mnew[r] = fmaxf(mrun[r], tm);
      alpha[r] = __expf(mrun[r] - mnew[r]);
      mrun[r] = mnew[r];
      rs[r] = 0.f;
    }
#pragma unroll
    for (int nb = 0; nb < 4; nb++)
#pragma unroll
      for (int r = 0; r < 4; r++) {
        float p = (sc[nb][r] > -1e29f) ? __expf(sc[nb][r] - mnew[r]) : 0.f;
        sc[nb][r] = p;
        rs[r] += p;
      }
#pragma unroll
    for (int r = 0; r < 4; r++) {
      float s = rs[r];
      s += __shfl_xor(s, 1);
      s += __shfl_xor(s, 2);
      s += __shfl_xor(s, 4);
      s += __shfl_xor(s, 8);
      lrun[r] = lrun[r] * alpha[r] + s;
    }
#pragma unroll
    for (int nb = 0; nb < 4; nb++)
#pragma unroll
      for (int r = 0; r < 4; r++) oacc[nb][r] *= alpha[r];
    // P: C-layout -> A-layout via wave-private LDS rows (no barrier needed)
#pragma unroll
    for (int nb = 0; nb < 4; nb++)
#pragma unroll
      for (int r = 0; r < 4; r++)
        Pl[(w * 16 + qd * 4 + r) * LDK + nb * 16 + lm] = (bf16)sc[nb][r];
    bf16x8 pa0 = *(const bf16x8*)&Pl[(w * 16 + lm) * LDK + qd * 8];
    bf16x8 pa1 = *(const bf16x8*)&Pl[(w * 16 + lm) * LDK + 32 + qd * 8];
#pragma unroll
    for (int nb = 0; nb < 4; nb++) {
      bf16x8 vf0 = *(const bf16x8*)&Vl[cur][(nb * 16 + lm) * LDK + qd * 8];
      bf16x8 vf1 = *(const bf16x8*)&Vl[cur][(nb * 16 + lm) * LDK + 32 + qd * 8];
      oacc[nb] = mfma_bf16(pa0, vf0, oacc[nb]);
      oacc[nb] = mfma_bf16(pa1, vf1, oacc[nb]);
    }
    // commit next tile to the other buffer, then one barrier
    if (more) {
      if (t < 64) kbl[nxt][t] = kbn;
      *(bf16x8*)&Kl[nxt][krow0 * LDK + ksg * 8] = kn0;
      *(bf16x8*)&Kl[nxt][krow1 * LDK + ksg * 8] = kn1;
#pragma unroll
      for (int j = 0; j < 8; j++) {
        Vl[nxt][(vsg0 * 8 + j) * LDK + vrow0] = vn0[j];
        Vl[nxt][(vsg1 * 8 + j) * LDK + vrow0] = vn1[j];
      }
      __syncthreads();
    }
  }
  // epilogue: scatter O rows back to original positions
#pragma unroll
  for (int r = 0; r < 4; r++) {
    int qs = qsl[w * 16 + qd * 4 + r];
    if (qs < 0) continue;
    float l = lrun[r];
    float inv = (l > 0.f) ? 1.f / l : 0.f;
#pragma unroll
    for (int nb = 0; nb < 4; nb++)
      O[((b * S_ + qs) * H_ + h) * DK_ + nb * 16 + lm] = (bf16)(oacc[nb][r] * inv);
  }
}

// ---------------------------------------------------------------- out GEMM
// C[m][n] = sum_k A[m][k]*Bt[n][k] + bias[n] -> fp32; 64x128 tile (512 blocks)
__global__ __launch_bounds__(256) void k_gout(const bf16* __restrict__ A,
                                              const bf16* __restrict__ Bt,
                                              const float* __restrict__ bias,
                                              float* __restrict__ out) {
  __shared__ __align__(16) bf16 Al[64 * 32];
  __shared__ __align__(16) bf16 Bl[128 * 32];
  const int t = threadIdx.x;
  const int lane = t & 63, w = t >> 6;
  const int lm = lane & 15, qd = lane >> 4;
  const int srow = lane >> 2, sseg = lane & 3;
  const int m0 = blockIdx.x * 64, n0 = blockIdx.y * 128;
  const int wm = w >> 1, wn = w & 1;

  f32x4 acc[2][4];
#pragma unroll
  for (int i = 0; i < 2; i++)
#pragma unroll
    for (int j = 0; j < 4; j++) acc[i][j] = zero4();

  for (int k0 = 0; k0 < D_; k0 += 32) {
    __syncthreads();
    load_lds16(&A[(m0 + w * 16 + srow) * D_ + k0 + sseg * 8],
               &Al[(w * 16) * 32]);
    load_lds16(&Bt[(n0 + w * 16 + srow) * D_ + k0 + sseg * 8],
               &Bl[(w * 16) * 32]);
    load_lds16(&Bt[(n0 + 64 + w * 16 + srow) * D_ + k0 + sseg * 8],
               &Bl[(64 + w * 16) * 32]);
    __syncthreads();
    bf16x8 af[2], bfr[4];
#pragma unroll
    for (int i = 0; i < 2; i++)
      af[i] = *(const bf16x8*)&Al[(wm * 32 + i * 16 + lm) * 32 + qd * 8];
#pragma unroll
    for (int j = 0; j < 4; j++)
      bfr[j] = *(const bf16x8*)&Bl[(wn * 64 + j * 16 + lm) * 32 + qd * 8];
#pragma unroll
    for (int i = 0; i < 2; i++)
#pragma unroll
      for (int j = 0; j < 4; j++) acc[i][j] = mfma_bf16(af[i], bfr[j], acc[i][j]);
  }
#pragma unroll
  for (int j = 0; j < 4; j++) {
    int n = n0 + wn * 64 + j * 16 + lm;
    float bv = bias[n];
#pragma unroll
    for (int i = 0; i < 2; i++) {
      int mbase = m0 + wm * 32 + i * 16 + qd * 4;
#pragma unroll
      for (int r = 0; r < 4; r++)
        out[(mbase + r) * D_ + n] = acc[i][j][r] + bv;
    }
  }
}

// ---------------------------------------------------------------- launch
extern "C" void kernel_launch(void* const* d_in, const int* in_sizes, int n_in,
                              void* d_out, int out_size, void* d_ws, size_t ws_size,
                              hipStream_t stream) {
  (void)in_sizes; (void)n_in; (void)out_size; (void)ws_size;
  const float* x  = (const float*)d_in[0];
  const float* Wq = (const float*)d_in[1];
  const float* bq = (const float*)d_in[2];
  const float* Wk = (const float*)d_in[3];
  const float* bk = (const float*)d_in[4];
  const float* Wv = (const float*)d_in[5];
  const float* bv = (const float*)d_in[6];
  const float* Wo = (const float*)d_in[7];
  const float* bo = (const float*)d_in[8];
  const float* R  = (const float*)d_in[9];

  char* ws = (char*)d_ws;
  bf16*  xh   = (bf16*)(ws + 0);          // 8 MB
  bf16*  Qb   = (bf16*)(ws + 8388608);    // 8 MB  [B,H,S,DK] (prescaled 1/8)
  bf16*  Kb   = (bf16*)(ws + 16777216);   // 8 MB  [B,H,S,DK]
  bf16*  Vb   = (bf16*)(ws + 25165824);   // 8 MB  [B,H,S,DK]
  bf16*  Ob   = (bf16*)(ws + 33554432);   // 8 MB  [B,S,H,DK]
  bf16*  Wtq  = (bf16*)(ws + 41943040);   // 2 MB each
  bf16*  Wtk  = (bf16*)(ws + 44040192);
  bf16*  Wtv  = (bf16*)(ws + 46137344);
  bf16*  Wto  = (bf16*)(ws + 48234496);
  int*   qbuf = (int*)(ws + 51380224);    // 256 KB each
  int*   kbuf = (int*)(ws + 51642368);
  float* bt   = (float*)(ws + 51904512);  // 1 KB
  bf16*  Pth  = (bf16*)(ws + 51905536);   // 512 KB each
  bf16*  Ptm  = (bf16*)(ws + 52429824);
  bf16*  Ptl  = (bf16*)(ws + 52954112);
  int*   qidxp= (int*)(ws + 53478400);    // 320 KB each
  int*   kidxp= (int*)(ws + 53806080);
  int2*  meta = (int2*)(ws + 54133760);   // 10 KB
  float* Lpart= (float*)(ws + 67108864);  // [64MB,80MB): 4 x 4MB fp32 partials

  k_prep<<<dim3(16, 16, 6), dim3(256), 0, stream>>>(
      Wq, Wk, Wv, Wo, x, bq, bk, R, Wtq, Wtk, Wtv, Wto, xh,
      Pth, Ptm, Ptl, bt);

  k_main<<<dim3(32, 56), dim3(256), 0, stream>>>(
      x, xh, Wtq, Wtk, Wtv, bq, bk, bv, Pth, Ptm, Ptl, Qb, Kb, Vb, Lpart);

  k_amax<<<dim3(256), dim3(256), 0, stream>>>(Lpart, bt, qbuf, kbuf);

  k_sort<<<dim3(32), dim3(256), 0, stream>>>(qbuf, kbuf, qidxp, kidxp, meta);

  k_attn<<<dim3(NQT, H_, B_), dim3(256), 0, stream>>>(Qb, Kb, Vb, qidxp, kidxp,
                                                      meta, Ob);

  k_gout<<<dim3(64, 8), dim3(256), 0, stream>>>(Ob, Wto, bo, (float*)d_out);
}